// Round 1
// 363.038 us; speedup vs baseline: 1.1396x; 1.1396x over previous
//
#include <hip/hip_runtime.h>
#include <cstddef>

#define NN 100000
#define EE 1600000
#define FF 128
#define BSH 9                        // 512 nodes per bucket
#define NB ((NN + 511) / 512)        // 196 buckets
#define EPB 4096                     // edges per binscatter block

typedef unsigned int uint;
typedef unsigned short ushort;
typedef short short8 __attribute__((ext_vector_type(8)));
typedef float f32x4 __attribute__((ext_vector_type(4)));

__device__ __forceinline__ ushort f2bf(float f) {
  uint u = __float_as_uint(f);
  uint r = u + 0x7fffu + ((u >> 16) & 1u);   // RNE
  return (ushort)(r >> 16);
}
__device__ __forceinline__ uint pack2(float a, float b) {
  return (uint)f2bf(a) | ((uint)f2bf(b) << 16);
}
// accumulate 8 bf16 (one uint4) into 8 fp32
__device__ __forceinline__ void acc8(float* a, uint4 v) {
  a[0] += __uint_as_float(v.x << 16);
  a[1] += __uint_as_float(v.x & 0xffff0000u);
  a[2] += __uint_as_float(v.y << 16);
  a[3] += __uint_as_float(v.y & 0xffff0000u);
  a[4] += __uint_as_float(v.z << 16);
  a[5] += __uint_as_float(v.z & 0xffff0000u);
  a[6] += __uint_as_float(v.w << 16);
  a[7] += __uint_as_float(v.w & 0xffff0000u);
}

// ---------------- x -> bf16 (8 floats / thread) ----------------
__global__ __launch_bounds__(256) void cvt_bf16(const float4* __restrict__ x,
                                                uint4* __restrict__ xb, int n8) {
  int i = blockIdx.x * 256 + threadIdx.x;
  if (i >= n8) return;
  float4 a = x[2 * i];
  float4 b = x[2 * i + 1];
  uint4 o;
  o.x = pack2(a.x, a.y);
  o.y = pack2(a.z, a.w);
  o.z = pack2(b.x, b.y);
  o.w = pack2(b.z, b.w);
  xb[i] = o;
}

// ---------------- w (fp32 [k][n]) -> wt (bf16 [n][k]) ----------------
__global__ __launch_bounds__(256) void cvt_wt(const float* __restrict__ w,
                                              ushort* __restrict__ wt) {
  int i = blockIdx.x * 256 + threadIdx.x;   // 0..16383
  int k = i >> 7, n = i & 127;
  wt[n * FF + k] = f2bf(w[(size_t)k * FF + n]);
}

// ---------------- bucket histogram (196 bins, LDS-privatized) ----------------
// Replaces the 100K-bin global-atomic hist: 1.6M global atomics -> 77K.
__global__ __launch_bounds__(256) void bucket_hist(const int* __restrict__ ei,
                                                   int* __restrict__ btot) {
  __shared__ int h[NB];
  const int t = threadIdx.x;
  for (int i = t; i < NB; i += 256) h[i] = 0;
  __syncthreads();
  const int e0 = blockIdx.x * EPB + t;
#pragma unroll
  for (int i = 0; i < 16; ++i) {
    int e = e0 + i * 256;
    if (e < EE) atomicAdd(&h[ei[EE + e] >> BSH], 1);
  }
  __syncthreads();
  for (int i = t; i < NB; i += 256)
    if (h[i]) atomicAdd(&btot[i], h[i]);
}

// ---------------- scan 196 bucket totals -> bases (one block) ----------------
__global__ __launch_bounds__(256) void bucket_scan(const int* __restrict__ btot,
                                                   int* __restrict__ bbase,
                                                   int* __restrict__ bcur,
                                                   int* __restrict__ offsets) {
  __shared__ int sd[256];
  const int t = threadIdx.x;
  sd[t] = (t < NB) ? btot[t] : 0;
  __syncthreads();
  for (int off = 1; off < 256; off <<= 1) {
    int v = 0;
    if (t >= off) v = sd[t - off];
    __syncthreads();
    if (t >= off) sd[t] += v;
    __syncthreads();
  }
  if (t < NB) {
    int b = t ? sd[t - 1] : 0;
    bbase[t] = b;
    bcur[t] = b;
  }
  if (t == 0) {
    bbase[NB] = EE;
    offsets[NN] = EE;
  }
}

// ---- binscatter: LDS counting-sort 4096 edges by bucket, coalesced dump ----
__global__ __launch_bounds__(256) void binscatter(const int* __restrict__ ei,
                                                  int* __restrict__ bcur,
                                                  uint2* __restrict__ pairs) {
  __shared__ uint2 lpair[EPB];     // 32 KB
  __shared__ int hcnt[256];        // hist, then local scatter cursor
  __shared__ int hincl[256];       // inclusive scan over buckets
  __shared__ int hbase[256];       // global base per bucket
  const int t = threadIdx.x;
  const int e0 = blockIdx.x * EPB;

  hcnt[t] = 0;
  __syncthreads();

  int es[16], ed[16];
#pragma unroll
  for (int i = 0; i < 16; ++i) {
    int e = e0 + t + i * 256;
    if (e < EE) {
      es[i] = ei[e];
      ed[i] = ei[EE + e];
      atomicAdd(&hcnt[ed[i] >> BSH], 1);
    } else {
      es[i] = -1;
      ed[i] = 0;
    }
  }
  __syncthreads();

  const int mycnt = hcnt[t];
  hincl[t] = mycnt;
  __syncthreads();
  for (int off = 1; off < 256; off <<= 1) {
    int tv = 0;
    if (t >= off) tv = hincl[t - off];
    __syncthreads();
    if (t >= off) hincl[t] += tv;
    __syncthreads();
  }
  // reserve global range (one atomic per non-empty bucket per block)
  if (t < NB && mycnt > 0) hbase[t] = atomicAdd(&bcur[t], mycnt);
  const int lbase = hincl[t] - mycnt;
  __syncthreads();
  hcnt[t] = lbase;                 // becomes local scatter cursor
  __syncthreads();

#pragma unroll
  for (int i = 0; i < 16; ++i) {
    if (es[i] >= 0) {
      int b = ed[i] >> BSH;
      int pos = atomicAdd(&hcnt[b], 1);
      lpair[pos] = make_uint2((uint)es[i], (uint)ed[i]);
    }
  }
  __syncthreads();

  const int total = hincl[255];
  for (int i = t; i < total; i += 256) {
    // smallest b with hincl[b] > i
    int lo = 0, hi = 255;
    while (lo < hi) {
      int mid = (lo + hi) >> 1;
      if (hincl[mid] > i) hi = mid; else lo = mid + 1;
    }
    int b = lo;
    int lb = b ? hincl[b - 1] : 0;
    pairs[(size_t)hbase[b] + (i - lb)] = lpair[i];
  }
}

// ---- fill2: one block per bucket. Counts its 512 nodes in LDS, scans,
//      writes per-node offsets, then scatters csr with LDS cursors.
//      (per-node counts derived here -> no global per-node histogram) ----
__global__ __launch_bounds__(512) void fill2(const uint2* __restrict__ pairs,
                                             const int* __restrict__ bbase,
                                             int* __restrict__ offsets,
                                             int* __restrict__ csr) {
  __shared__ int cnt[512];
  __shared__ int cur[512];
  const int t = threadIdx.x;
  const int b = blockIdx.x;
  const int v0 = b << BSH;
  cnt[t] = 0;
  __syncthreads();
  const int pbeg = bbase[b];
  const int pend = bbase[b + 1];
  // pass 1: count edges per node (LDS atomics; segment is L2-hot afterwards)
  for (int j = pbeg + t; j < pend; j += 512)
    atomicAdd(&cnt[(int)pairs[j].y - v0], 1);
  __syncthreads();
  const int my = cnt[t];
  cur[t] = my;                       // inclusive-scan buffer
  __syncthreads();
  for (int off = 1; off < 512; off <<= 1) {
    int v = 0;
    if (t >= off) v = cur[t - off];
    __syncthreads();
    if (t >= off) cur[t] += v;
    __syncthreads();
  }
  const int goff = pbeg + cur[t] - my;   // global CSR start for node v0+t
  const int v = v0 + t;
  if (v < NN) offsets[v] = goff;
  __syncthreads();
  cur[t] = goff;                     // becomes scatter cursor
  __syncthreads();
  // pass 2: scatter (csr writes stay within the bucket's contiguous range)
  for (int j = pbeg + t; j < pend; j += 512) {
    uint2 p = pairs[j];
    int pos = atomicAdd(&cur[(int)p.y - v0], 1);
    csr[pos] = (int)p.x;
  }
}

// ---------------- gather-reduce (bf16 rows -> bf16 rows) ----------------
__global__ __launch_bounds__(256) void gather_bf16(const uint4* __restrict__ feat,
                                                   const int* __restrict__ offsets,
                                                   const int* __restrict__ csr,
                                                   ushort* __restrict__ out) {
  int t = blockIdx.x * 256 + threadIdx.x;
  int g = t >> 4;
  int l = t & 15;
  if (g >= NN) return;
  int beg = offsets[g];
  int end = offsets[g + 1];
  float acc[8] = {};
  acc8(acc, feat[(size_t)g * 16 + l]);           // self term
  int j = beg;
  for (; j + 4 <= end; j += 4) {
    int i0 = csr[j], i1 = csr[j + 1], i2 = csr[j + 2], i3 = csr[j + 3];
    uint4 v0 = feat[(size_t)i0 * 16 + l];
    uint4 v1 = feat[(size_t)i1 * 16 + l];
    uint4 v2 = feat[(size_t)i2 * 16 + l];
    uint4 v3 = feat[(size_t)i3 * 16 + l];
    acc8(acc, v0); acc8(acc, v1); acc8(acc, v2); acc8(acc, v3);
  }
  for (; j < end; ++j) acc8(acc, feat[(size_t)csr[j] * 16 + l]);
  uint4 o;
  o.x = pack2(acc[0], acc[1]);
  o.y = pack2(acc[2], acc[3]);
  o.z = pack2(acc[4], acc[5]);
  o.w = pack2(acc[6], acc[7]);
  ((uint4*)(out + (size_t)g * FF))[l] = o;
}

// ---------------- bf16 MFMA GEMM (no LDS) ----------------
template <bool BN, bool OUT16>
__global__ __launch_bounds__(256) void gemm_mfma(const ushort* __restrict__ a,
    const ushort* __restrict__ bt, const float* __restrict__ bias,
    const float* __restrict__ gamma, const float* __restrict__ beta,
    const float* __restrict__ rmean, const float* __restrict__ rvar,
    void* __restrict__ out0, int nrows)
{
  const int tid = threadIdx.x;
  const int wv = tid >> 6;
  const int l = tid & 63;
  const int lane16 = l & 15;
  const int quad = l >> 4;
  const int rowbase = blockIdx.x * 128 + wv * 32;

  f32x4 acc[2][8] = {};

  for (int kc = 0; kc < FF; kc += 32) {
    short8 af[2];
#pragma unroll
    for (int rt = 0; rt < 2; ++rt) {
      int r = min(rowbase + rt * 16 + lane16, nrows - 1);
      af[rt] = *(const short8*)(a + (size_t)r * FF + kc + quad * 8);
    }
#pragma unroll
    for (int ct = 0; ct < 8; ++ct) {
      int n = ct * 16 + lane16;
      short8 bf = *(const short8*)(bt + n * FF + kc + quad * 8);
      acc[0][ct] = __builtin_amdgcn_mfma_f32_16x16x32_bf16(af[0], bf, acc[0][ct], 0, 0, 0);
      acc[1][ct] = __builtin_amdgcn_mfma_f32_16x16x32_bf16(af[1], bf, acc[1][ct], 0, 0, 0);
    }
  }

  float sc[8], sh[8];
#pragma unroll
  for (int ct = 0; ct < 8; ++ct) {
    int c = ct * 16 + lane16;
    if (BN) {
      float s = gamma[c] * rsqrtf(rvar[c] + 1e-5f);
      sc[ct] = s;
      sh[ct] = (bias[c] - rmean[c]) * s + beta[c];
    } else {
      sc[ct] = 1.0f;
      sh[ct] = bias[c];
    }
  }

#pragma unroll
  for (int rt = 0; rt < 2; ++rt) {
#pragma unroll
    for (int reg = 0; reg < 4; ++reg) {
      int r = rowbase + rt * 16 + quad * 4 + reg;
      if (r < nrows) {
#pragma unroll
        for (int ct = 0; ct < 8; ++ct) {
          int c = ct * 16 + lane16;
          float v = fmaf(acc[rt][ct][reg], sc[ct], sh[ct]);
          if (BN) v = fmaxf(v, 0.0f);
          if (OUT16) ((ushort*)out0)[(size_t)r * FF + c] = f2bf(v);
          else       ((float*)out0)[(size_t)r * FF + c] = v;
        }
      }
    }
  }
}

extern "C" void kernel_launch(void* const* d_in, const int* in_sizes, int n_in,
                              void* d_out, int out_size, void* d_ws, size_t ws_size,
                              hipStream_t stream) {
  const float* x     = (const float*)d_in[0];
  const int*   ei    = (const int*)d_in[1];
  const float* w0    = (const float*)d_in[2];
  const float* b0    = (const float*)d_in[3];
  const float* gamma = (const float*)d_in[4];
  const float* beta  = (const float*)d_in[5];
  const float* rmean = (const float*)d_in[6];
  const float* rvar  = (const float*)d_in[7];
  const float* w1    = (const float*)d_in[8];
  const float* b1    = (const float*)d_in[9];
  float* out = (float*)d_out;

  // workspace layout (pairs placed 8B-aligned right after bf16 buffers)
  ushort* sb  = (ushort*)d_ws;                    // NN*FF
  ushort* xb  = sb + (size_t)NN * FF;             // NN*FF
  ushort* hb  = xb + (size_t)NN * FF;             // NN*FF
  ushort* wt0 = hb + (size_t)NN * FF;             // 128*128
  ushort* wt1 = wt0 + FF * FF;                    // 128*128
  uint2* pairs  = (uint2*)(wt1 + FF * FF);        // EE uint2 (12.8 MB)
  int* csr      = (int*)(pairs + (size_t)EE);     // EE
  int* offsets  = csr + EE;                       // NN+1
  int* bcur     = offsets + NN + 1;               // NB
  int* bbase    = bcur + NB;                      // NB+1
  int* btot     = bbase + NB + 1;                 // NB

  const int cvb = (NN * FF / 8 + 255) / 256;      // 6250
  const int gatherb = (NN * 16 + 255) / 256;      // 6250
  const int gemmb = (NN + 127) / 128;             // 782
  const int binb = (EE + EPB - 1) / EPB;          // 391

  // ---- CSR build (no per-node global histogram) ----
  (void)hipMemsetAsync(btot, 0, (size_t)NB * sizeof(int), stream);
  bucket_hist<<<binb, 256, 0, stream>>>(ei, btot);
  bucket_scan<<<1, 256, 0, stream>>>(btot, bbase, bcur, offsets);
  binscatter<<<binb, 256, 0, stream>>>(ei, bcur, pairs);
  fill2<<<NB, 512, 0, stream>>>(pairs, bbase, offsets, csr);

  // ---- precision converts ----
  cvt_bf16<<<cvb, 256, 0, stream>>>((const float4*)x, (uint4*)xb, NN * FF / 8);
  cvt_wt<<<64, 256, 0, stream>>>(w0, wt0);
  cvt_wt<<<64, 256, 0, stream>>>(w1, wt1);

  // ---- layer 1 ----
  gather_bf16<<<gatherb, 256, 0, stream>>>((const uint4*)xb, offsets, csr, sb);
  gemm_mfma<true, true><<<gemmb, 256, 0, stream>>>(sb, wt0, b0, gamma, beta,
                                                   rmean, rvar, (void*)hb, NN);
  // ---- layer 2 ----
  gather_bf16<<<gatherb, 256, 0, stream>>>((const uint4*)hb, offsets, csr, sb);
  gemm_mfma<false, false><<<gemmb, 256, 0, stream>>>(sb, wt1, b1, nullptr, nullptr,
                                                     nullptr, nullptr, (void*)out, NN);
}

// Round 2
// 360.406 us; speedup vs baseline: 1.1479x; 1.0073x over previous
//
#include <hip/hip_runtime.h>
#include <cstddef>

#define NN 100000
#define EE 1600000
#define FF 128
#define BSH 9                        // 512 nodes per bucket
#define NB ((NN + 511) / 512)        // 196 buckets
#define EPB 4096                     // edges per binscatter block

typedef unsigned int uint;
typedef unsigned short ushort;
typedef short short8 __attribute__((ext_vector_type(8)));
typedef float f32x4 __attribute__((ext_vector_type(4)));

__device__ __forceinline__ ushort f2bf(float f) {
  uint u = __float_as_uint(f);
  uint r = u + 0x7fffu + ((u >> 16) & 1u);   // RNE
  return (ushort)(r >> 16);
}
__device__ __forceinline__ uint pack2(float a, float b) {
  return (uint)f2bf(a) | ((uint)f2bf(b) << 16);
}
// accumulate 8 bf16 (one uint4) into 8 fp32
__device__ __forceinline__ void acc8(float* a, uint4 v) {
  a[0] += __uint_as_float(v.x << 16);
  a[1] += __uint_as_float(v.x & 0xffff0000u);
  a[2] += __uint_as_float(v.y << 16);
  a[3] += __uint_as_float(v.y & 0xffff0000u);
  a[4] += __uint_as_float(v.z << 16);
  a[5] += __uint_as_float(v.z & 0xffff0000u);
  a[6] += __uint_as_float(v.w << 16);
  a[7] += __uint_as_float(v.w & 0xffff0000u);
}

// ---------------- x -> bf16 (8 floats / thread) ----------------
__global__ __launch_bounds__(256) void cvt_bf16(const float4* __restrict__ x,
                                                uint4* __restrict__ xb, int n8) {
  int i = blockIdx.x * 256 + threadIdx.x;
  if (i >= n8) return;
  float4 a = x[2 * i];
  float4 b = x[2 * i + 1];
  uint4 o;
  o.x = pack2(a.x, a.y);
  o.y = pack2(a.z, a.w);
  o.z = pack2(b.x, b.y);
  o.w = pack2(b.z, b.w);
  xb[i] = o;
}

// ---------------- w (fp32 [k][n]) -> wt (bf16 [n][k]) ----------------
__global__ __launch_bounds__(256) void cvt_wt(const float* __restrict__ w,
                                              ushort* __restrict__ wt) {
  int i = blockIdx.x * 256 + threadIdx.x;   // 0..16383
  int k = i >> 7, n = i & 127;
  wt[n * FF + k] = f2bf(w[(size_t)k * FF + n]);
}

// ---------------- bucket histogram (196 bins, LDS-privatized) ----------------
__global__ __launch_bounds__(256) void bucket_hist(const int* __restrict__ ei,
                                                   int* __restrict__ btot) {
  __shared__ int h[NB];
  const int t = threadIdx.x;
  for (int i = t; i < NB; i += 256) h[i] = 0;
  __syncthreads();
  const int e0 = blockIdx.x * EPB + t;
#pragma unroll
  for (int i = 0; i < 16; ++i) {
    int e = e0 + i * 256;
    if (e < EE) atomicAdd(&h[ei[EE + e] >> BSH], 1);
  }
  __syncthreads();
  for (int i = t; i < NB; i += 256)
    if (h[i]) atomicAdd(&btot[i], h[i]);
}

// ---------------- scan 196 bucket totals -> bases (one block) ----------------
__global__ __launch_bounds__(256) void bucket_scan(const int* __restrict__ btot,
                                                   int* __restrict__ bbase,
                                                   int* __restrict__ bcur,
                                                   int* __restrict__ offsets) {
  __shared__ int sd[256];
  const int t = threadIdx.x;
  sd[t] = (t < NB) ? btot[t] : 0;
  __syncthreads();
  for (int off = 1; off < 256; off <<= 1) {
    int v = 0;
    if (t >= off) v = sd[t - off];
    __syncthreads();
    if (t >= off) sd[t] += v;
    __syncthreads();
  }
  if (t < NB) {
    int b = t ? sd[t - 1] : 0;
    bbase[t] = b;
    bcur[t] = b;
  }
  if (t == 0) {
    bbase[NB] = EE;
    offsets[NN] = EE;
  }
}

// ---- binscatter: LDS counting-sort 4096 edges by bucket, coalesced dump ----
__global__ __launch_bounds__(256) void binscatter(const int* __restrict__ ei,
                                                  int* __restrict__ bcur,
                                                  uint2* __restrict__ pairs) {
  __shared__ uint2 lpair[EPB];     // 32 KB
  __shared__ int hcnt[256];        // hist, then local scatter cursor
  __shared__ int hincl[256];       // inclusive scan over buckets
  __shared__ int hbase[256];       // global base per bucket
  const int t = threadIdx.x;
  const int e0 = blockIdx.x * EPB;

  hcnt[t] = 0;
  __syncthreads();

  int es[16], ed[16];
#pragma unroll
  for (int i = 0; i < 16; ++i) {
    int e = e0 + t + i * 256;
    if (e < EE) {
      es[i] = ei[e];
      ed[i] = ei[EE + e];
      atomicAdd(&hcnt[ed[i] >> BSH], 1);
    } else {
      es[i] = -1;
      ed[i] = 0;
    }
  }
  __syncthreads();

  const int mycnt = hcnt[t];
  hincl[t] = mycnt;
  __syncthreads();
  for (int off = 1; off < 256; off <<= 1) {
    int tv = 0;
    if (t >= off) tv = hincl[t - off];
    __syncthreads();
    if (t >= off) hincl[t] += tv;
    __syncthreads();
  }
  // reserve global range (one atomic per non-empty bucket per block)
  if (t < NB && mycnt > 0) hbase[t] = atomicAdd(&bcur[t], mycnt);
  const int lbase = hincl[t] - mycnt;
  __syncthreads();
  hcnt[t] = lbase;                 // becomes local scatter cursor
  __syncthreads();

#pragma unroll
  for (int i = 0; i < 16; ++i) {
    if (es[i] >= 0) {
      int b = ed[i] >> BSH;
      int pos = atomicAdd(&hcnt[b], 1);
      lpair[pos] = make_uint2((uint)es[i], (uint)ed[i]);
    }
  }
  __syncthreads();

  const int total = hincl[255];
  for (int i = t; i < total; i += 256) {
    // smallest b with hincl[b] > i
    int lo = 0, hi = 255;
    while (lo < hi) {
      int mid = (lo + hi) >> 1;
      if (hincl[mid] > i) hi = mid; else lo = mid + 1;
    }
    int b = lo;
    int lb = b ? hincl[b - 1] : 0;
    pairs[(size_t)hbase[b] + (i - lb)] = lpair[i];
  }
}

// ---- fill2: one block per bucket. Counts its 512 nodes in LDS, scans,
//      writes per-node offsets, then scatters csr with LDS cursors. ----
__global__ __launch_bounds__(512) void fill2(const uint2* __restrict__ pairs,
                                             const int* __restrict__ bbase,
                                             int* __restrict__ offsets,
                                             int* __restrict__ csr) {
  __shared__ int cnt[512];
  __shared__ int cur[512];
  const int t = threadIdx.x;
  const int b = blockIdx.x;
  const int v0 = b << BSH;
  cnt[t] = 0;
  __syncthreads();
  const int pbeg = bbase[b];
  const int pend = bbase[b + 1];
  for (int j = pbeg + t; j < pend; j += 512)
    atomicAdd(&cnt[(int)pairs[j].y - v0], 1);
  __syncthreads();
  const int my = cnt[t];
  cur[t] = my;
  __syncthreads();
  for (int off = 1; off < 512; off <<= 1) {
    int v = 0;
    if (t >= off) v = cur[t - off];
    __syncthreads();
    if (t >= off) cur[t] += v;
    __syncthreads();
  }
  const int goff = pbeg + cur[t] - my;
  const int v = v0 + t;
  if (v < NN) offsets[v] = goff;
  __syncthreads();
  cur[t] = goff;
  __syncthreads();
  for (int j = pbeg + t; j < pend; j += 512) {
    uint2 p = pairs[j];
    int pos = atomicAdd(&cur[(int)p.y - v0], 1);
    csr[pos] = (int)p.x;
  }
}

// ---------------- gather-reduce (bf16 rows -> bf16 rows) ----------------
// Unroll-8 for memory-level parallelism: 8 independent index loads, then 8
// independent 16B row loads in flight per lane (was 4 -> latency-limited).
__global__ __launch_bounds__(256) void gather_bf16(const uint4* __restrict__ feat,
                                                   const int* __restrict__ offsets,
                                                   const int* __restrict__ csr,
                                                   ushort* __restrict__ out) {
  int t = blockIdx.x * 256 + threadIdx.x;
  int g = t >> 4;
  int l = t & 15;
  if (g >= NN) return;
  int beg = offsets[g];
  int end = offsets[g + 1];
  float acc[8] = {};
  acc8(acc, feat[(size_t)g * 16 + l]);           // self term
  int j = beg;
  for (; j + 8 <= end; j += 8) {
    int idx[8];
#pragma unroll
    for (int i = 0; i < 8; ++i) idx[i] = csr[j + i];
    uint4 v[8];
#pragma unroll
    for (int i = 0; i < 8; ++i) v[i] = feat[(size_t)idx[i] * 16 + l];
#pragma unroll
    for (int i = 0; i < 8; ++i) acc8(acc, v[i]);
  }
  if (j + 4 <= end) {
    int idx[4];
#pragma unroll
    for (int i = 0; i < 4; ++i) idx[i] = csr[j + i];
    uint4 v[4];
#pragma unroll
    for (int i = 0; i < 4; ++i) v[i] = feat[(size_t)idx[i] * 16 + l];
#pragma unroll
    for (int i = 0; i < 4; ++i) acc8(acc, v[i]);
    j += 4;
  }
  for (; j < end; ++j) acc8(acc, feat[(size_t)csr[j] * 16 + l]);
  uint4 o;
  o.x = pack2(acc[0], acc[1]);
  o.y = pack2(acc[2], acc[3]);
  o.z = pack2(acc[4], acc[5]);
  o.w = pack2(acc[6], acc[7]);
  ((uint4*)(out + (size_t)g * FF))[l] = o;
}

// ---------------- bf16 MFMA GEMM (no LDS) ----------------
template <bool BN, bool OUT16>
__global__ __launch_bounds__(256) void gemm_mfma(const ushort* __restrict__ a,
    const ushort* __restrict__ bt, const float* __restrict__ bias,
    const float* __restrict__ gamma, const float* __restrict__ beta,
    const float* __restrict__ rmean, const float* __restrict__ rvar,
    void* __restrict__ out0, int nrows)
{
  const int tid = threadIdx.x;
  const int wv = tid >> 6;
  const int l = tid & 63;
  const int lane16 = l & 15;
  const int quad = l >> 4;
  const int rowbase = blockIdx.x * 128 + wv * 32;

  f32x4 acc[2][8] = {};

  for (int kc = 0; kc < FF; kc += 32) {
    short8 af[2];
#pragma unroll
    for (int rt = 0; rt < 2; ++rt) {
      int r = min(rowbase + rt * 16 + lane16, nrows - 1);
      af[rt] = *(const short8*)(a + (size_t)r * FF + kc + quad * 8);
    }
#pragma unroll
    for (int ct = 0; ct < 8; ++ct) {
      int n = ct * 16 + lane16;
      short8 bf = *(const short8*)(bt + n * FF + kc + quad * 8);
      acc[0][ct] = __builtin_amdgcn_mfma_f32_16x16x32_bf16(af[0], bf, acc[0][ct], 0, 0, 0);
      acc[1][ct] = __builtin_amdgcn_mfma_f32_16x16x32_bf16(af[1], bf, acc[1][ct], 0, 0, 0);
    }
  }

  float sc[8], sh[8];
#pragma unroll
  for (int ct = 0; ct < 8; ++ct) {
    int c = ct * 16 + lane16;
    if (BN) {
      float s = gamma[c] * rsqrtf(rvar[c] + 1e-5f);
      sc[ct] = s;
      sh[ct] = (bias[c] - rmean[c]) * s + beta[c];
    } else {
      sc[ct] = 1.0f;
      sh[ct] = bias[c];
    }
  }

#pragma unroll
  for (int rt = 0; rt < 2; ++rt) {
#pragma unroll
    for (int reg = 0; reg < 4; ++reg) {
      int r = rowbase + rt * 16 + quad * 4 + reg;
      if (r < nrows) {
#pragma unroll
        for (int ct = 0; ct < 8; ++ct) {
          int c = ct * 16 + lane16;
          float v = fmaf(acc[rt][ct][reg], sc[ct], sh[ct]);
          if (BN) v = fmaxf(v, 0.0f);
          if (OUT16) ((ushort*)out0)[(size_t)r * FF + c] = f2bf(v);
          else       ((float*)out0)[(size_t)r * FF + c] = v;
        }
      }
    }
  }
}

extern "C" void kernel_launch(void* const* d_in, const int* in_sizes, int n_in,
                              void* d_out, int out_size, void* d_ws, size_t ws_size,
                              hipStream_t stream) {
  const float* x     = (const float*)d_in[0];
  const int*   ei    = (const int*)d_in[1];
  const float* w0    = (const float*)d_in[2];
  const float* b0    = (const float*)d_in[3];
  const float* gamma = (const float*)d_in[4];
  const float* beta  = (const float*)d_in[5];
  const float* rmean = (const float*)d_in[6];
  const float* rvar  = (const float*)d_in[7];
  const float* w1    = (const float*)d_in[8];
  const float* b1    = (const float*)d_in[9];
  float* out = (float*)d_out;

  // workspace layout
  ushort* sb  = (ushort*)d_ws;                    // NN*FF
  ushort* xb  = sb + (size_t)NN * FF;             // NN*FF
  ushort* hb  = xb + (size_t)NN * FF;             // NN*FF
  ushort* wt0 = hb + (size_t)NN * FF;             // 128*128
  ushort* wt1 = wt0 + FF * FF;                    // 128*128
  uint2* pairs  = (uint2*)(wt1 + FF * FF);        // EE uint2 (12.8 MB)
  int* csr      = (int*)(pairs + (size_t)EE);     // EE
  int* offsets  = csr + EE;                       // NN+1
  int* bcur     = offsets + NN + 1;               // NB
  int* bbase    = bcur + NB;                      // NB+1
  int* btot     = bbase + NB + 1;                 // NB

  const int cvb = (NN * FF / 8 + 255) / 256;      // 6250
  const int gatherb = (NN * 16 + 255) / 256;      // 6250
  const int gemmb = (NN + 127) / 128;             // 782
  const int binb = (EE + EPB - 1) / EPB;          // 391

  // ---- CSR build (no per-node global histogram) ----
  (void)hipMemsetAsync(btot, 0, (size_t)NB * sizeof(int), stream);
  bucket_hist<<<binb, 256, 0, stream>>>(ei, btot);
  bucket_scan<<<1, 256, 0, stream>>>(btot, bbase, bcur, offsets);
  binscatter<<<binb, 256, 0, stream>>>(ei, bcur, pairs);
  fill2<<<NB, 512, 0, stream>>>(pairs, bbase, offsets, csr);

  // ---- precision converts ----
  cvt_bf16<<<cvb, 256, 0, stream>>>((const float4*)x, (uint4*)xb, NN * FF / 8);
  cvt_wt<<<64, 256, 0, stream>>>(w0, wt0);
  cvt_wt<<<64, 256, 0, stream>>>(w1, wt1);

  // ---- layer 1 ----
  gather_bf16<<<gatherb, 256, 0, stream>>>((const uint4*)xb, offsets, csr, sb);
  gemm_mfma<true, true><<<gemmb, 256, 0, stream>>>(sb, wt0, b0, gamma, beta,
                                                   rmean, rvar, (void*)hb, NN);
  // ---- layer 2 ----
  gather_bf16<<<gatherb, 256, 0, stream>>>((const uint4*)hb, offsets, csr, sb);
  gemm_mfma<false, false><<<gemmb, 256, 0, stream>>>(sb, wt1, b1, nullptr, nullptr,
                                                     nullptr, nullptr, (void*)out, NN);
}